// Round 1
// 242.039 us; speedup vs baseline: 1.7813x; 1.7813x over previous
//
#include <hip/hip_runtime.h>
#include <stdint.h>

/* AdditiveAttention (B=4, Q=256, K=1024, D=512, H=256)
 * out[b,i,v] = sum_j softmax_j(sum_h tanh(q[b,i,h]+k[b,j,h])*wv[h]) * values[b,j,v],
 * masked to j < valid_lens[b].  OUTPUT IS FLOAT32 (R20 finding).
 *
 * R21 restructure: occupancy. Old grids left 1 block/CU (Occupancy 11.8%,
 * VALUBusy 50%). New: attn = 256 blocks x 1024 thr (16 waves/CU), projections
 * 512 blocks each. Algebra: sum_h w*tanh = sumW - 2*sum_h w/(1+e^{2x}); sumW
 * is constant per row -> cancels in softmax. Projections store pre-scaled
 * values (2*log2e folded in) so the score inner loop is add+exp2+add+rcp+fma
 * (2 trans, 3 VALU) per element. */

#define NB 4
#define NQ 256
#define NK 1024
#define ND 512
#define NH 256
#define QROWS 4

#define C2L2E 2.8853900817779268f   /* 2*log2(e) */
#define L2E   1.4426950408889634f   /* log2(e)   */

/* 8-class valid_lens decode: {i32,i64,f32,f64,i16,f16,bf16,fallback}. */
__device__ void ff_vldec(const int* p, int* v) {
  bool ok = true;
  for (int i = 0; i < 4; ++i) { int x = p[i]; if (x < 1 || x > NK) ok = false; }
  if (ok) { for (int i = 0; i < 4; ++i) v[i] = p[i]; return; }
  ok = true;
  for (int i = 0; i < 4; ++i) {
    if (p[2 * i + 1] != 0) ok = false;
    int x = p[2 * i]; if (x < 1 || x > NK) ok = false;
  }
  if (ok) { for (int i = 0; i < 4; ++i) v[i] = p[2 * i]; return; }
  ok = true;
  for (int i = 0; i < 4; ++i) {
    union { int i; float f; } u; u.i = p[i];
    if (!(u.f >= 1.0f && u.f <= 1024.0f && u.f == floorf(u.f))) ok = false;
  }
  if (ok) {
    for (int i = 0; i < 4; ++i) { union { int i; float f; } u; u.i = p[i]; v[i] = (int)u.f; }
    return;
  }
  ok = true;
  for (int i = 0; i < 4; ++i) {
    union { long long l; double d; } u;
    u.l = ((long long)p[2 * i + 1] << 32) | (unsigned int)p[2 * i];
    if (!(u.d >= 1.0 && u.d <= 1024.0 && u.d == floor(u.d))) ok = false;
  }
  if (ok) {
    for (int i = 0; i < 4; ++i) {
      union { long long l; double d; } u;
      u.l = ((long long)p[2 * i + 1] << 32) | (unsigned int)p[2 * i];
      v[i] = (int)u.d;
    }
    return;
  }
  const uint16_t* hh = (const uint16_t*)p;
  const short*    s  = (const short*)p;
  ok = true;
  for (int i = 0; i < 4; ++i) { int x = s[i]; if (x < 1 || x > NK) ok = false; }
  if (ok) { for (int i = 0; i < 4; ++i) v[i] = s[i]; return; }
  ok = true;
  for (int i = 0; i < 4; ++i) {
    union { uint16_t u; _Float16 h; } u; u.u = hh[i];
    float f = (float)u.h;
    if (!(f >= 1.0f && f <= 1024.0f && f == floorf(f))) ok = false;
  }
  if (ok) {
    for (int i = 0; i < 4; ++i) {
      union { uint16_t u; _Float16 h; } u; u.u = hh[i];
      v[i] = (int)(float)u.h;
    }
    return;
  }
  ok = true;
  for (int i = 0; i < 4; ++i) {
    union { uint32_t u; float f; } u; u.u = ((uint32_t)hh[i]) << 16;
    if (!(u.f >= 1.0f && u.f <= 1028.0f)) ok = false;
  }
  if (ok) {
    for (int i = 0; i < 4; ++i) {
      union { uint32_t u; float f; } u; u.u = ((uint32_t)hh[i]) << 16;
      int x = (int)(u.f + 0.5f); if (x > NK) x = NK; v[i] = x;
    }
    return;
  }
  for (int i = 0; i < 4; ++i) v[i] = NK;  /* fail-safe: unmasked */
}

/* qp[r][h] = C2L2E * sum_d in[r][d] * Wq[h][d],  r over B*Q (contiguous).
 * 2 rows/block -> 512 blocks (8 waves/CU). */
__global__ __launch_bounds__(256) void ff_projq(
    const float* __restrict__ in, const float* __restrict__ W,
    float* __restrict__ out)
{
  __shared__ float xs[2 * ND];
  const int t = threadIdx.x;
  const size_t r0 = (size_t)blockIdx.x * 2;
  const float* src = in + r0 * ND;
  ((float4*)xs)[t] = ((const float4*)src)[t];   /* 256 thr x 16B = 2 rows */
  __syncthreads();
  float a0 = 0.f, a1 = 0.f;
  const float* wr = W + (size_t)t * ND;
  #pragma unroll 4
  for (int c = 0; c < ND / 4; ++c) {
    float4 w  = ((const float4*)wr)[c];
    float4 x0 = *(const float4*)&xs[c * 4];
    float4 x1 = *(const float4*)&xs[ND + c * 4];
    a0 += w.x*x0.x + w.y*x0.y + w.z*x0.z + w.w*x0.w;
    a1 += w.x*x1.x + w.y*x1.y + w.z*x1.z + w.w*x1.w;
  }
  out[r0 * NH + t]       = C2L2E * a0;
  out[(r0 + 1) * NH + t] = C2L2E * a1;
}

/* kp[b][h][k] = C2L2E * sum_d keys[b][k][d] * Wk[h][d]  (transposed store).
 * 8 rows/block -> 512 blocks. */
__global__ __launch_bounds__(256) void ff_projk(
    const float* __restrict__ in, const float* __restrict__ W,
    float* __restrict__ out)
{
  __shared__ float xs[8 * ND];                   /* 16 KB */
  const int t = threadIdx.x;
  const int r0g = blockIdx.x * 8;
  const int b = r0g >> 10, rk = r0g & 1023;
  const float* src = in + (size_t)r0g * ND;
  #pragma unroll
  for (int i = 0; i < 4; ++i)
    ((float4*)xs)[t + 256 * i] = ((const float4*)src)[t + 256 * i];
  __syncthreads();
  float acc[8];
  #pragma unroll
  for (int i = 0; i < 8; ++i) acc[i] = 0.f;
  const float* wr = W + (size_t)t * ND;
  #pragma unroll 2
  for (int c = 0; c < ND / 4; ++c) {
    float4 w = ((const float4*)wr)[c];
    #pragma unroll
    for (int i = 0; i < 8; ++i) {
      float4 x = *(const float4*)&xs[i * ND + c * 4];
      acc[i] += w.x*x.x + w.y*x.y + w.z*x.z + w.w*x.w;
    }
  }
  float* o = out + ((size_t)b * NH + t) * NK + rk;
  *(float4*)o       = make_float4(C2L2E*acc[0], C2L2E*acc[1], C2L2E*acc[2], C2L2E*acc[3]);
  *(float4*)(o + 4) = make_float4(C2L2E*acc[4], C2L2E*acc[5], C2L2E*acc[6], C2L2E*acc[7]);
}

/* Fused scores + masked softmax + PV.  1024 threads, 4 q-rows per block.
 * Phase1: thread owns k=t, 4 rows; score' = sum_h (-2*wv_h)/(1+exp2(q'+k'))
 * (the +sumW constant cancels in softmax; q',k' pre-scaled by 2*log2e).
 * Phase2: 4 waves/row softmax with cross-wave LDS combine.
 * Phase3: split-k PV (4 quarters), LDS partial reduce.  F32 output. */
__global__ __launch_bounds__(1024) void ff_attn(
    const float* __restrict__ qp, const float* __restrict__ kp,
    const float* __restrict__ vals, const int* __restrict__ vlraw,
    const float* __restrict__ wvp, float* __restrict__ out)
{
  __shared__ float qs[NH * QROWS];        /* [h][row], pre-scaled      4 KB */
  __shared__ float ws[NH];                /* -2*wv                     1 KB */
  __shared__ float st[NK * QROWS];        /* [k][row] scores->probs   16 KB */
  __shared__ float pm[16], psm[16];
  __shared__ float part[4 * QROWS * ND];  /* split-k partials         32 KB */

  const int t  = threadIdx.x;
  const int q0 = blockIdx.x * QROWS;
  const int b  = blockIdx.y;

  {
    const float* qsrc = qp + ((size_t)b * NQ + q0) * NH;
    const int row = t >> 8, h = t & 255;
    qs[h * QROWS + row] = qsrc[t];        /* qsrc[row*NH+h] == qsrc[t] */
    if (t < NH) ws[t] = -2.0f * wvp[t];
  }
  __syncthreads();

  int vls[4];
  ff_vldec(vlraw, vls);
  const int vl = vls[b];

  /* ---- phase 1: scores, thread owns k = t ---- */
  float a0 = 0.f, a1 = 0.f, a2 = 0.f, a3 = 0.f;
  {
    const float* kvp = kp + (size_t)b * NH * NK + t;
    #pragma unroll 4
    for (int h = 0; h < NH; ++h) {
      float  kv = kvp[(size_t)h * NK];
      float4 q4 = *(const float4*)(qs + h * QROWS);
      float  w  = ws[h];
      a0 += w * __builtin_amdgcn_rcpf(1.0f + __builtin_amdgcn_exp2f(q4.x + kv));
      a1 += w * __builtin_amdgcn_rcpf(1.0f + __builtin_amdgcn_exp2f(q4.y + kv));
      a2 += w * __builtin_amdgcn_rcpf(1.0f + __builtin_amdgcn_exp2f(q4.z + kv));
      a3 += w * __builtin_amdgcn_rcpf(1.0f + __builtin_amdgcn_exp2f(q4.w + kv));
    }
  }
  {
    const bool ok = (t < vl);
    *(float4*)&st[t * 4] = make_float4(ok ? a0 : -1e6f, ok ? a1 : -1e6f,
                                       ok ? a2 : -1e6f, ok ? a3 : -1e6f);
  }
  __syncthreads();

  /* ---- phase 2: masked softmax, 4 waves per row ---- */
  {
    const int wid = t >> 6, lane = t & 63;
    const int row = wid >> 2, seg = wid & 3;
    const int kb = seg * 256 + lane;
    float v0 = st[(kb      ) * 4 + row];
    float v1 = st[(kb +  64) * 4 + row];
    float v2 = st[(kb + 128) * 4 + row];
    float v3 = st[(kb + 192) * 4 + row];
    float m = fmaxf(fmaxf(v0, v1), fmaxf(v2, v3));
    for (int o = 32; o; o >>= 1) m = fmaxf(m, __shfl_xor(m, o));
    if (lane == 0) pm[wid] = m;
    __syncthreads();
    m = fmaxf(fmaxf(pm[row*4+0], pm[row*4+1]), fmaxf(pm[row*4+2], pm[row*4+3]));
    float e0 = __builtin_amdgcn_exp2f((v0 - m) * L2E);
    float e1 = __builtin_amdgcn_exp2f((v1 - m) * L2E);
    float e2 = __builtin_amdgcn_exp2f((v2 - m) * L2E);
    float e3 = __builtin_amdgcn_exp2f((v3 - m) * L2E);
    float sm = e0 + e1 + e2 + e3;
    for (int o = 32; o; o >>= 1) sm += __shfl_xor(sm, o);
    if (lane == 0) psm[wid] = sm;
    __syncthreads();
    const float S = psm[row*4+0] + psm[row*4+1] + psm[row*4+2] + psm[row*4+3];
    const float rr = 1.0f / S;
    st[(kb      ) * 4 + row] = e0 * rr;
    st[(kb +  64) * 4 + row] = e1 * rr;
    st[(kb + 128) * 4 + row] = e2 * rr;
    st[(kb + 192) * 4 + row] = e3 * rr;
  }
  __syncthreads();

  /* ---- phase 3: PV, split-k quarters; values[b] read once per block ---- */
  {
    const int kq = t >> 8, c2 = (t & 255) * 2;
    const float* vb = vals + (size_t)b * NK * ND + c2;
    float ox0=0.f, oy0=0.f, ox1=0.f, oy1=0.f;
    float ox2=0.f, oy2=0.f, ox3=0.f, oy3=0.f;
    const int k0 = kq * 256;
    #pragma unroll 2
    for (int k = k0; k < k0 + 256; ++k) {
      float2 v2 = *(const float2*)(vb + (size_t)k * ND);
      float4 a  = *(const float4*)&st[k * 4];
      ox0 += a.x * v2.x; oy0 += a.x * v2.y;
      ox1 += a.y * v2.x; oy1 += a.y * v2.y;
      ox2 += a.z * v2.x; oy2 += a.z * v2.y;
      ox3 += a.w * v2.x; oy3 += a.w * v2.y;
    }
    float* pp = &part[(size_t)kq * QROWS * ND + c2];
    *(float2*)(pp         ) = make_float2(ox0, oy0);
    *(float2*)(pp +     ND) = make_float2(ox1, oy1);
    *(float2*)(pp + 2 * ND) = make_float2(ox2, oy2);
    *(float2*)(pp + 3 * ND) = make_float2(ox3, oy3);
  }
  __syncthreads();
  {
    const int r = t >> 8, c2 = (t & 255) * 2;
    const float* pp = &part[(size_t)r * ND + c2];
    float2 s = make_float2(0.f, 0.f);
    #pragma unroll
    for (int kq = 0; kq < 4; ++kq) {
      float2 p = *(const float2*)(pp + (size_t)kq * QROWS * ND);
      s.x += p.x; s.y += p.y;
    }
    *(float2*)(out + ((size_t)b * NQ + q0 + r) * ND + c2) = s;
  }
}

extern "C" void kernel_launch(void* const* d_in, const int* in_sizes, int n_in,
                              void* d_out, int out_size, void* d_ws, size_t ws_size,
                              hipStream_t stream) {
  const float* queries = (const float*)d_in[0];
  const float* keys    = (const float*)d_in[1];
  const float* values  = (const float*)d_in[2];
  const int*   vlens   = (const int*)d_in[3];
  const float* Wq      = (const float*)d_in[4];
  const float* Wk      = (const float*)d_in[5];
  const float* wv      = (const float*)d_in[6];
  float* out = (float*)d_out;               /* F32 OUTPUT */

  float* qp = (float*)d_ws;                 /* [B][Q][H]  1 MB, pre-scaled */
  float* kp = qp + (size_t)NB * NQ * NH;    /* [B][H][K]  4 MB, pre-scaled */

  ff_projq<<<dim3((NB * NQ) / 2), 256, 0, stream>>>(queries, Wq, qp);
  ff_projk<<<dim3((NB * NK) / 8), 256, 0, stream>>>(keys, Wk, kp);
  ff_attn<<<dim3(NQ / QROWS, NB), 1024, 0, stream>>>(qp, kp, values, vlens, wv, out);
}

// Round 2
// 209.560 us; speedup vs baseline: 2.0574x; 1.1550x over previous
//
#include <hip/hip_runtime.h>
#include <stdint.h>

/* AdditiveAttention (B=4, Q=256, K=1024, D=512, H=256)
 * out[b,i,v] = sum_j softmax_j(sum_h tanh(q[b,i,h]+k[b,j,h])*wv[h]) * values[b,j,v],
 * masked to j < valid_lens[b].  OUTPUT IS FLOAT32 (R20 finding).
 *
 * R22: projection overhaul. Old projq/projk had each thread reading its own
 * W row (lanes stride 2KB -> 64 lines/wave-load, ~8x L2 sector waste, ~115us
 * for 8.5us of FMA). New: ff_wt pre-transposes W into [d4][h] float4 layout
 * (prescale 2*log2e folded), ff_proj reads W coalesced (16B/lane contiguous)
 * and x as wave-uniform scalar loads (SMEM pipe) -> FMA-bound. attn: unroll
 * 8 in score + PV loops (was 4/2) to double loads-in-flight (latency-BW
 * product was marginal at 16 waves). */

#define NB 4
#define NQ 256
#define NK 1024
#define ND 512
#define NH 256
#define QROWS 4
#define PR 8

#define C2L2E 2.8853900817779268f   /* 2*log2(e) */
#define L2E   1.4426950408889634f   /* log2(e)   */

/* 8-class valid_lens decode: {i32,i64,f32,f64,i16,f16,bf16,fallback}. */
__device__ void ff_vldec(const int* p, int* v) {
  bool ok = true;
  for (int i = 0; i < 4; ++i) { int x = p[i]; if (x < 1 || x > NK) ok = false; }
  if (ok) { for (int i = 0; i < 4; ++i) v[i] = p[i]; return; }
  ok = true;
  for (int i = 0; i < 4; ++i) {
    if (p[2 * i + 1] != 0) ok = false;
    int x = p[2 * i]; if (x < 1 || x > NK) ok = false;
  }
  if (ok) { for (int i = 0; i < 4; ++i) v[i] = p[2 * i]; return; }
  ok = true;
  for (int i = 0; i < 4; ++i) {
    union { int i; float f; } u; u.i = p[i];
    if (!(u.f >= 1.0f && u.f <= 1024.0f && u.f == floorf(u.f))) ok = false;
  }
  if (ok) {
    for (int i = 0; i < 4; ++i) { union { int i; float f; } u; u.i = p[i]; v[i] = (int)u.f; }
    return;
  }
  ok = true;
  for (int i = 0; i < 4; ++i) {
    union { long long l; double d; } u;
    u.l = ((long long)p[2 * i + 1] << 32) | (unsigned int)p[2 * i];
    if (!(u.d >= 1.0 && u.d <= 1024.0 && u.d == floor(u.d))) ok = false;
  }
  if (ok) {
    for (int i = 0; i < 4; ++i) {
      union { long long l; double d; } u;
      u.l = ((long long)p[2 * i + 1] << 32) | (unsigned int)p[2 * i];
      v[i] = (int)u.d;
    }
    return;
  }
  const uint16_t* hh = (const uint16_t*)p;
  const short*    s  = (const short*)p;
  ok = true;
  for (int i = 0; i < 4; ++i) { int x = s[i]; if (x < 1 || x > NK) ok = false; }
  if (ok) { for (int i = 0; i < 4; ++i) v[i] = s[i]; return; }
  ok = true;
  for (int i = 0; i < 4; ++i) {
    union { uint16_t u; _Float16 h; } u; u.u = hh[i];
    float f = (float)u.h;
    if (!(f >= 1.0f && f <= 1024.0f && f == floorf(f))) ok = false;
  }
  if (ok) {
    for (int i = 0; i < 4; ++i) {
      union { uint16_t u; _Float16 h; } u; u.u = hh[i];
      v[i] = (int)(float)u.h;
    }
    return;
  }
  ok = true;
  for (int i = 0; i < 4; ++i) {
    union { uint32_t u; float f; } u; u.u = ((uint32_t)hh[i]) << 16;
    if (!(u.f >= 1.0f && u.f <= 1028.0f)) ok = false;
  }
  if (ok) {
    for (int i = 0; i < 4; ++i) {
      union { uint32_t u; float f; } u; u.u = ((uint32_t)hh[i]) << 16;
      int x = (int)(u.f + 0.5f); if (x > NK) x = NK; v[i] = x;
    }
    return;
  }
  for (int i = 0; i < 4; ++i) v[i] = NK;  /* fail-safe: unmasked */
}

/* Transpose W[h][d] -> WT float4 #(d4*NH+h) = C2L2E * W[h][4d4..4d4+3].
 * Read coalesced along d; scatter-write 16B chunks (1MB total, trivial). */
__global__ __launch_bounds__(256) void ff_wt(
    const float* __restrict__ Wq, const float* __restrict__ Wk,
    float* __restrict__ WTq, float* __restrict__ WTk)
{
  const int idx = blockIdx.x * 256 + threadIdx.x;   /* 0..32767 */
  const int d4 = idx & 127, h = idx >> 7;
  const float* src = blockIdx.y ? Wk : Wq;
  float*       dst = blockIdx.y ? WTk : WTq;
  float4 w = *(const float4*)(src + (size_t)h * ND + d4 * 4);
  w.x *= C2L2E; w.y *= C2L2E; w.z *= C2L2E; w.w *= C2L2E;
  *(float4*)(dst + ((size_t)d4 * NH + h) * 4) = w;
}

/* Merged projection: blocks [0,128) -> queries (qp[r][h], pre-scaled),
 * blocks [128,640) -> keys (kp[b][h][k], pre-scaled, transposed store).
 * Thread owns h=t for PR=8 rows; W coalesced float4, x wave-uniform (s_load). */
__global__ __launch_bounds__(256) void ff_proj(
    const float* __restrict__ q_in, const float* __restrict__ k_in,
    const float* __restrict__ WTq, const float* __restrict__ WTk,
    float* __restrict__ qp, float* __restrict__ kp)
{
  const int t = threadIdx.x;
  const bool isq = blockIdx.x < (NB * NQ / PR);
  const int g = isq ? blockIdx.x : (blockIdx.x - NB * NQ / PR);
  const float* xin = (isq ? q_in : k_in) + (size_t)g * PR * ND;
  const float* WT  = isq ? WTq : WTk;

  float acc[PR];
  #pragma unroll
  for (int r = 0; r < PR; ++r) acc[r] = 0.f;

  #pragma unroll 2
  for (int d4 = 0; d4 < ND / 4; ++d4) {
    float4 w = *(const float4*)(WT + ((size_t)d4 * NH + t) * 4);
    #pragma unroll
    for (int r = 0; r < PR; ++r) {
      float4 x = *(const float4*)(xin + (size_t)r * ND + d4 * 4);
      acc[r] += w.x * x.x + w.y * x.y + w.z * x.z + w.w * x.w;
    }
  }

  if (isq) {
    float* o = qp + (size_t)g * PR * NH + t;
    #pragma unroll
    for (int r = 0; r < PR; ++r) o[(size_t)r * NH] = acc[r];
  } else {
    const int r0 = g * PR;
    const int bb = r0 >> 10, rk = r0 & (NK - 1);
    float* o = kp + ((size_t)bb * NH + t) * NK + rk;
    *(float4*)o       = make_float4(acc[0], acc[1], acc[2], acc[3]);
    *(float4*)(o + 4) = make_float4(acc[4], acc[5], acc[6], acc[7]);
  }
}

/* Fused scores + masked softmax + PV.  1024 threads, 4 q-rows per block.
 * Phase1: thread owns k=t; score' = sum_h (-2*wv_h)/(1+exp2(q'+k'))
 * (sumW cancels in softmax; q',k' pre-scaled by 2*log2e).
 * Phase2: 4 waves/row softmax. Phase3: split-k PV + LDS reduce. F32 out. */
__global__ __launch_bounds__(1024) void ff_attn(
    const float* __restrict__ qp, const float* __restrict__ kp,
    const float* __restrict__ vals, const int* __restrict__ vlraw,
    const float* __restrict__ wvp, float* __restrict__ out)
{
  __shared__ float qs[NH * QROWS];        /* [h][row], pre-scaled      4 KB */
  __shared__ float ws[NH];                /* -2*wv                     1 KB */
  __shared__ float st[NK * QROWS];        /* [k][row] scores->probs   16 KB */
  __shared__ float pm[16], psm[16];
  __shared__ float part[4 * QROWS * ND];  /* split-k partials         32 KB */

  const int t  = threadIdx.x;
  const int q0 = blockIdx.x * QROWS;
  const int b  = blockIdx.y;

  {
    const float* qsrc = qp + ((size_t)b * NQ + q0) * NH;
    const int row = t >> 8, h = t & 255;
    qs[h * QROWS + row] = qsrc[t];        /* qsrc[row*NH+h] == qsrc[t] */
    if (t < NH) ws[t] = -2.0f * wvp[t];
  }
  __syncthreads();

  int vls[4];
  ff_vldec(vlraw, vls);
  const int vl = vls[b];

  /* ---- phase 1: scores, thread owns k = t ---- */
  float a0 = 0.f, a1 = 0.f, a2 = 0.f, a3 = 0.f;
  {
    const float* kvp = kp + (size_t)b * NH * NK + t;
    #pragma unroll 8
    for (int h = 0; h < NH; ++h) {
      float  kv = kvp[(size_t)h * NK];
      float4 q4 = *(const float4*)(qs + h * QROWS);
      float  w  = ws[h];
      a0 += w * __builtin_amdgcn_rcpf(1.0f + __builtin_amdgcn_exp2f(q4.x + kv));
      a1 += w * __builtin_amdgcn_rcpf(1.0f + __builtin_amdgcn_exp2f(q4.y + kv));
      a2 += w * __builtin_amdgcn_rcpf(1.0f + __builtin_amdgcn_exp2f(q4.z + kv));
      a3 += w * __builtin_amdgcn_rcpf(1.0f + __builtin_amdgcn_exp2f(q4.w + kv));
    }
  }
  {
    const bool ok = (t < vl);
    *(float4*)&st[t * 4] = make_float4(ok ? a0 : -1e6f, ok ? a1 : -1e6f,
                                       ok ? a2 : -1e6f, ok ? a3 : -1e6f);
  }
  __syncthreads();

  /* ---- phase 2: masked softmax, 4 waves per row ---- */
  {
    const int wid = t >> 6, lane = t & 63;
    const int row = wid >> 2, seg = wid & 3;
    const int kb = seg * 256 + lane;
    float v0 = st[(kb      ) * 4 + row];
    float v1 = st[(kb +  64) * 4 + row];
    float v2 = st[(kb + 128) * 4 + row];
    float v3 = st[(kb + 192) * 4 + row];
    float m = fmaxf(fmaxf(v0, v1), fmaxf(v2, v3));
    for (int o = 32; o; o >>= 1) m = fmaxf(m, __shfl_xor(m, o));
    if (lane == 0) pm[wid] = m;
    __syncthreads();
    m = fmaxf(fmaxf(pm[row*4+0], pm[row*4+1]), fmaxf(pm[row*4+2], pm[row*4+3]));
    float e0 = __builtin_amdgcn_exp2f((v0 - m) * L2E);
    float e1 = __builtin_amdgcn_exp2f((v1 - m) * L2E);
    float e2 = __builtin_amdgcn_exp2f((v2 - m) * L2E);
    float e3 = __builtin_amdgcn_exp2f((v3 - m) * L2E);
    float sm = e0 + e1 + e2 + e3;
    for (int o = 32; o; o >>= 1) sm += __shfl_xor(sm, o);
    if (lane == 0) psm[wid] = sm;
    __syncthreads();
    const float S = psm[row*4+0] + psm[row*4+1] + psm[row*4+2] + psm[row*4+3];
    const float rr = 1.0f / S;
    st[(kb      ) * 4 + row] = e0 * rr;
    st[(kb +  64) * 4 + row] = e1 * rr;
    st[(kb + 128) * 4 + row] = e2 * rr;
    st[(kb + 192) * 4 + row] = e3 * rr;
  }
  __syncthreads();

  /* ---- phase 3: PV, split-k quarters; values[b] read once per block ---- */
  {
    const int kq = t >> 8, c2 = (t & 255) * 2;
    const float* vb = vals + (size_t)b * NK * ND + c2;
    float ox0=0.f, oy0=0.f, ox1=0.f, oy1=0.f;
    float ox2=0.f, oy2=0.f, ox3=0.f, oy3=0.f;
    const int k0 = kq * 256;
    #pragma unroll 8
    for (int k = k0; k < k0 + 256; ++k) {
      float2 v2 = *(const float2*)(vb + (size_t)k * ND);
      float4 a  = *(const float4*)&st[k * 4];
      ox0 += a.x * v2.x; oy0 += a.x * v2.y;
      ox1 += a.y * v2.x; oy1 += a.y * v2.y;
      ox2 += a.z * v2.x; oy2 += a.z * v2.y;
      ox3 += a.w * v2.x; oy3 += a.w * v2.y;
    }
    float* pp = &part[(size_t)kq * QROWS * ND + c2];
    *(float2*)(pp         ) = make_float2(ox0, oy0);
    *(float2*)(pp +     ND) = make_float2(ox1, oy1);
    *(float2*)(pp + 2 * ND) = make_float2(ox2, oy2);
    *(float2*)(pp + 3 * ND) = make_float2(ox3, oy3);
  }
  __syncthreads();
  {
    const int r = t >> 8, c2 = (t & 255) * 2;
    const float* pp = &part[(size_t)r * ND + c2];
    float2 s = make_float2(0.f, 0.f);
    #pragma unroll
    for (int kq = 0; kq < 4; ++kq) {
      float2 p = *(const float2*)(pp + (size_t)kq * QROWS * ND);
      s.x += p.x; s.y += p.y;
    }
    *(float2*)(out + ((size_t)b * NQ + q0 + r) * ND + c2) = s;
  }
}

extern "C" void kernel_launch(void* const* d_in, const int* in_sizes, int n_in,
                              void* d_out, int out_size, void* d_ws, size_t ws_size,
                              hipStream_t stream) {
  const float* queries = (const float*)d_in[0];
  const float* keys    = (const float*)d_in[1];
  const float* values  = (const float*)d_in[2];
  const int*   vlens   = (const int*)d_in[3];
  const float* Wq      = (const float*)d_in[4];
  const float* Wk      = (const float*)d_in[5];
  const float* wv      = (const float*)d_in[6];
  float* out = (float*)d_out;               /* F32 OUTPUT */

  float* qp  = (float*)d_ws;                /* [B][Q][H]   1 MB, pre-scaled */
  float* kp  = qp  + (size_t)NB * NQ * NH;  /* [B][H][K]   4 MB, pre-scaled */
  float* wtq = kp  + (size_t)NB * NH * NK;  /* [D/4][H]x4  512 KB */
  float* wtk = wtq + (size_t)(ND / 4) * NH * 4; /*         512 KB */

  ff_wt  <<<dim3(128, 2), 256, 0, stream>>>(Wq, Wk, wtq, wtk);
  ff_proj<<<dim3(NB * NQ / PR + NB * NK / PR), 256, 0, stream>>>(
      queries, keys, wtq, wtk, qp, kp);
  ff_attn<<<dim3(NQ / QROWS, NB), 1024, 0, stream>>>(qp, kp, values, vlens, wv, out);
}